// Round 1
// baseline (746.016 us; speedup 1.0000x reference)
//
#include <hip/hip_runtime.h>
#include <stdint.h>

// Problem constants
#define L_   3969         // patches
#define LP   3972         // padded L (mult of 4, for float4 loads)
#define EPS_ 1e-5f
#define LOG2E 1.4426950408889634f

// workspace layout (float offsets). Total 5,131,808 floats = 20.5 MB
#define OFF_MF   0          // [2][64][LP] fg mean
#define OFF_SF   508416     // fg var
#define OFF_MB   1016832    // bg mean
#define OFF_SB   1525248    // bg var
#define OFF_TOKF 2033664    // [2][64][LP]
#define OFF_TOKB 2542080
#define OFF_NSTD 3050496    // [2][LP][64]
#define OFF_PACC 3558912    // [2 mh][2 b][LP][64]
#define OFF_PM   4575744    // [2][2][LP]
#define OFF_PD   4591632
#define OFF_WT   4607520    // [2 t][64 c][64 k][64 d]

// ---------------- K0: transpose weights to [t][c][k][d] ----------------
__global__ void k0_wt(const float* __restrict__ wf, const float* __restrict__ wb,
                      float* __restrict__ ws) {
    int c = blockIdx.x, t = blockIdx.y;
    const float* w = t ? wb : wf;
    float* wt = ws + OFF_WT + (t * 64 + c) * 4096;
    __shared__ __align__(16) float tile[64][65];
    int k = threadIdx.x & 63, dq = threadIdx.x >> 6;
#pragma unroll
    for (int u = 0; u < 16; ++u) {
        int d = dq * 16 + u;
        tile[d][k] = w[(d * 64 + c) * 64 + k];
    }
    __syncthreads();
    int d2 = threadIdx.x & 63, kq = threadIdx.x >> 6;
#pragma unroll
    for (int u = 0; u < 16; ++u) {
        int kk = kq * 16 + u;
        wt[kk * 64 + d2] = tile[d2][kk];
    }
}

// ---------------- K1: per-patch fg/bg stats ----------------
// grid (63 i, 64 c, 2 b), 256 threads
__global__ void k1_stats(const float* __restrict__ x, const float* __restrict__ mask,
                         float* __restrict__ ws) {
    int i = blockIdx.x, c = blockIdx.y, b = blockIdx.z;
    __shared__ float xs[8 * 256];
    __shared__ float ms[8 * 256];
    __shared__ float pS[5][256];
    int t = threadIdx.x;
    const float* xr = x + (((b * 64 + c) * 256) + i * 4) * 256;
    const float* mr = mask + (b * 256 + i * 4) * 256;
#pragma unroll
    for (int r = 0; r < 8; ++r) {
        xs[r * 256 + t] = xr[r * 256 + t];
        ms[r * 256 + t] = mr[r * 256 + t];
    }
    __syncthreads();
    int q = t >> 6, j = t & 63;
    float Sa = 0, Qa = 0, Sf = 0, Qf = 0, Nf = 0;
    if (j < 63) {
#pragma unroll
        for (int rr = 0; rr < 2; ++rr) {
            int base = (q * 2 + rr) * 256 + j * 4;
#pragma unroll
            for (int cc = 0; cc < 8; ++cc) {
                float v = xs[base + cc], m = ms[base + cc];
                Sa += v; Qa += v * v; Sf += v * m; Qf += v * v * m; Nf += m;
            }
        }
    }
    pS[0][t] = Sa; pS[1][t] = Qa; pS[2][t] = Sf; pS[3][t] = Qf; pS[4][t] = Nf;
    __syncthreads();
    if (q == 0 && j < 63) {
        Sa = pS[0][j] + pS[0][j + 64] + pS[0][j + 128] + pS[0][j + 192];
        Qa = pS[1][j] + pS[1][j + 64] + pS[1][j + 128] + pS[1][j + 192];
        Sf = pS[2][j] + pS[2][j + 64] + pS[2][j + 128] + pS[2][j + 192];
        Qf = pS[3][j] + pS[3][j + 64] + pS[3][j + 128] + pS[3][j + 192];
        Nf = pS[4][j] + pS[4][j + 64] + pS[4][j + 128] + pS[4][j + 192];
        float nb = 64.0f - Nf;
        float muf = Sf / (Nf + EPS_);
        float vaf = (Qf - 2.f * muf * Sf + Nf * muf * muf) / (Nf + EPS_);
        float Sb = Sa - Sf, Qb = Qa - Qf;
        float mub = Sb / (nb + EPS_);
        float vab = (Qb - 2.f * mub * Sb + nb * mub * mub) / (nb + EPS_);
        int idx = (b * 64 + c) * LP + i * 63 + j;
        ws[OFF_MF + idx] = muf; ws[OFF_SF + idx] = vaf;
        ws[OFF_MB + idx] = mub; ws[OFF_SB + idx] = vab;
    }
}

// ---------------- K2: tok GEMM (on-the-fly in_f/in_b), split-K-4 ----------------
// grid (32 lt, 4 kc, 4 t*2+b), 128 threads
__global__ __launch_bounds__(128)
void k2_tok(const float* __restrict__ x, const float* __restrict__ mask,
            const float* __restrict__ wsc, float* __restrict__ ws) {
    int lt = blockIdx.x, kc = blockIdx.y;
    int t = blockIdx.z >> 1, b = blockIdx.z & 1;
    int l0 = lt * 128;
    int tid = threadIdx.x;
    __shared__ __align__(16) float wl[64 * 64];     // [k][d]
    __shared__ __align__(16) float inl[64 * 132];   // [k][l]
    const float* MU = wsc + (t ? OFF_MB : OFF_MF);
    const float* VA = wsc + (t ? OFF_SB : OFF_SF);
    const float* WT = wsc + OFF_WT + t * 262144;

    int l = l0 + tid;
    bool valid = l < L_;
    int rowbase = 0;
    uint64_t pmb = 0;
    if (valid) {
        int il = l / 63, jl = l - il * 63;
        rowbase = (il * 4) * 256 + jl * 4;
        const float* mp = mask + b * 65536 + rowbase;
#pragma unroll
        for (int k = 0; k < 64; ++k) {
            if (mp[(k >> 3) * 256 + (k & 7)] != 0.0f) pmb |= (1ull << k);
        }
    }
    if (t) pmb = ~pmb;  // bg: x-side where mask==0

    float acc[8][8];
#pragma unroll
    for (int u = 0; u < 8; ++u)
#pragma unroll
        for (int v = 0; v < 8; ++v) acc[u][v] = 0.f;

    int ty = tid >> 4;  // d-group (8 d)
    int tx = tid & 15;  // l chunks 4tx and 64+4tx

    for (int c = kc * 16; c < kc * 16 + 16; ++c) {
        __syncthreads();
        // build in column (this thread's l)
        {
            float mu = 0.f, inv = 0.f;
            if (valid) {
                mu = MU[(b * 64 + c) * LP + l];
                inv = 1.0f / VA[(b * 64 + c) * LP + l];
            }
            const float* xp = x + (b * 64 + c) * 65536 + rowbase;
#pragma unroll
            for (int k = 0; k < 64; ++k) {
                float in = 0.f;
                if (valid) {
                    float v = xp[(k >> 3) * 256 + (k & 7)];
                    in = ((pmb >> k) & 1) ? (v - mu) * inv : mu;
                }
                inl[k * 132 + tid] = in;
            }
        }
        // stage w tile [k][d]
#pragma unroll
        for (int it = 0; it < 8; ++it) {
            int chunk = it * 128 + tid;
            int k = chunk >> 4, d4 = chunk & 15;
            *(float4*)&wl[k * 64 + d4 * 4] = *(const float4*)&WT[(c * 64 + k) * 64 + d4 * 4];
        }
        __syncthreads();
#pragma unroll 4
        for (int k = 0; k < 64; ++k) {
            float4 A0 = *(const float4*)&wl[k * 64 + 8 * ty];
            float4 A1 = *(const float4*)&wl[k * 64 + 8 * ty + 4];
            float4 B0 = *(const float4*)&inl[k * 132 + 4 * tx];
            float4 B1 = *(const float4*)&inl[k * 132 + 64 + 4 * tx];
            float a[8] = {A0.x, A0.y, A0.z, A0.w, A1.x, A1.y, A1.z, A1.w};
            float bb[8] = {B0.x, B0.y, B0.z, B0.w, B1.x, B1.y, B1.z, B1.w};
#pragma unroll
            for (int u = 0; u < 8; ++u)
#pragma unroll
                for (int v = 0; v < 8; ++v) acc[u][v] = fmaf(a[u], bb[v], acc[u][v]);
        }
    }
    float* tok = ws + (t ? OFF_TOKB : OFF_TOKF) + b * 64 * LP;
#pragma unroll
    for (int u = 0; u < 8; ++u) {
        int d = 8 * ty + u;
#pragma unroll
        for (int v = 0; v < 8; ++v) {
            int ll = (v < 4) ? (4 * tx + v) : (64 + 4 * tx + (v - 4));
            int lg = l0 + ll;
            if (lg < L_) atomicAdd(&tok[d * LP + lg], acc[u][v]);
        }
    }
}

// ---------------- K3: fused logits+bias -> online softmax -> S.sb (split-m-2) ----------------
// grid (63 lt, 2 mh, 2 b), 256 threads
__global__ __launch_bounds__(256)
void k3_attn(const float* __restrict__ wsc, const float* __restrict__ rpb,
             float* __restrict__ ws) {
    int lt = blockIdx.x, mh = blockIdx.y, b = blockIdx.z;
    int l0 = lt * 64;
    int mstart = mh ? 1984 : 0;
    int mend = mh ? L_ : 1984;
    int tid = threadIdx.x;
    int ty = tid >> 4, tx = tid & 15;

    __shared__ __align__(16) float tf[64 * 68];    // [c][l]
    __shared__ __align__(16) float tbp[64 * 68];   // phase1: tb [c][m]; then pL [l][m]
    __shared__ __align__(16) float sbT[64 * 68];   // [m][c]

    const float* TFg = wsc + OFF_TOKF + b * 64 * LP;
    const float* TBg = wsc + OFF_TOKB + b * 64 * LP;
    const float* SBg = wsc + OFF_SB + b * 64 * LP;

#pragma unroll
    for (int it = 0; it < 16; ++it) {
        int e = it * 256 + tid;
        int c = e >> 6, ll = e & 63;
        int lg = l0 + ll;
        tf[c * 68 + ll] = (lg < L_) ? TFg[c * LP + lg] : 0.f;
    }

    int ril[4], rjl[4];
    bool rvalid[4];
#pragma unroll
    for (int i = 0; i < 4; ++i) {
        int rl = l0 + 4 * ty + i;
        rvalid[i] = rl < L_;
        int il = rvalid[i] ? (rl / 63) : 0;
        ril[i] = il; rjl[i] = rvalid[i] ? (rl - il * 63) : 0;
    }
    float mrun[4] = {-1e30f, -1e30f, -1e30f, -1e30f};
    float drun[4] = {0.f, 0.f, 0.f, 0.f};
    float acc[4][4];
#pragma unroll
    for (int i = 0; i < 4; ++i)
#pragma unroll
        for (int u = 0; u < 4; ++u) acc[i][u] = 0.f;

    int nmt = (mend - mstart + 63) >> 6;
    for (int mt = 0; mt < nmt; ++mt) {
        int m0 = mstart + mt * 64;
        __syncthreads();  // previous phase2 done before overwriting tiles
#pragma unroll
        for (int it = 0; it < 16; ++it) {
            int e = it * 256 + tid;
            int c = e >> 6, mm = e & 63;
            int mg = m0 + mm;
            float tv = 0.f, sv = 0.f;
            if (mg < mend) { tv = TBg[c * LP + mg]; sv = SBg[c * LP + mg]; }
            tbp[c * 68 + mm] = tv;
            sbT[mm * 68 + c] = sv;
        }
        __syncthreads();
        // phase1: logits
        float z[4][4];
        int mim[4], mjm[4]; bool mv[4];
#pragma unroll
        for (int j = 0; j < 4; ++j) {
            int mg = m0 + 4 * tx + j;
            mv[j] = mg < mend;
            int im = mv[j] ? (mg / 63) : 0;
            mim[j] = im; mjm[j] = mv[j] ? (mg - im * 63) : 0;
        }
#pragma unroll
        for (int i = 0; i < 4; ++i)
#pragma unroll
            for (int j = 0; j < 4; ++j)
                z[i][j] = (rvalid[i] && mv[j])
                              ? rpb[(ril[i] - mim[j] + 62) * 125 + (rjl[i] - mjm[j] + 62)]
                              : -1e30f;
#pragma unroll 4
        for (int c = 0; c < 64; ++c) {
            float4 av = *(const float4*)&tf[c * 68 + 4 * ty];
            float4 bv = *(const float4*)&tbp[c * 68 + 4 * tx];
            float a[4] = {av.x, av.y, av.z, av.w};
            float bb[4] = {bv.x, bv.y, bv.z, bv.w};
#pragma unroll
            for (int i = 0; i < 4; ++i)
#pragma unroll
                for (int j = 0; j < 4; ++j) z[i][j] = fmaf(a[i], bb[j], z[i][j]);
        }
        // online softmax update
        float p[4][4], mnew[4], alpha[4], rsum[4];
#pragma unroll
        for (int i = 0; i < 4; ++i) {
            float v = fmaxf(fmaxf(z[i][0], z[i][1]), fmaxf(z[i][2], z[i][3]));
            v = fmaxf(v, __shfl_xor(v, 1, 16));
            v = fmaxf(v, __shfl_xor(v, 2, 16));
            v = fmaxf(v, __shfl_xor(v, 4, 16));
            v = fmaxf(v, __shfl_xor(v, 8, 16));
            mnew[i] = fmaxf(mrun[i], v);
            alpha[i] = exp2f((mrun[i] - mnew[i]) * LOG2E);
            float s = 0.f;
#pragma unroll
            for (int j = 0; j < 4; ++j) {
                p[i][j] = exp2f((z[i][j] - mnew[i]) * LOG2E);
                s += p[i][j];
            }
            s += __shfl_xor(s, 1, 16);
            s += __shfl_xor(s, 2, 16);
            s += __shfl_xor(s, 4, 16);
            s += __shfl_xor(s, 8, 16);
            rsum[i] = s;
        }
#pragma unroll
        for (int i = 0; i < 4; ++i) {
            drun[i] = drun[i] * alpha[i] + rsum[i];
            mrun[i] = mnew[i];
#pragma unroll
            for (int u = 0; u < 4; ++u) acc[i][u] *= alpha[i];
        }
        __syncthreads();  // all phase1 tb reads done; tbp becomes pL
#pragma unroll
        for (int i = 0; i < 4; ++i)
            *(float4*)&tbp[(4 * ty + i) * 68 + 4 * tx] =
                make_float4(p[i][0], p[i][1], p[i][2], p[i][3]);
        __syncthreads();
        // phase2: acc[l][c] += p[l][m] * sb[c][m]
#pragma unroll 4
        for (int mc = 0; mc < 16; ++mc) {
            float4 s0 = *(const float4*)&sbT[(4 * mc + 0) * 68 + 4 * tx];
            float4 s1 = *(const float4*)&sbT[(4 * mc + 1) * 68 + 4 * tx];
            float4 s2 = *(const float4*)&sbT[(4 * mc + 2) * 68 + 4 * tx];
            float4 s3 = *(const float4*)&sbT[(4 * mc + 3) * 68 + 4 * tx];
            float sw[4][4] = {{s0.x, s0.y, s0.z, s0.w},
                              {s1.x, s1.y, s1.z, s1.w},
                              {s2.x, s2.y, s2.z, s2.w},
                              {s3.x, s3.y, s3.z, s3.w}};
#pragma unroll
            for (int i = 0; i < 4; ++i) {
                float4 pv = *(const float4*)&tbp[(4 * ty + i) * 68 + 4 * mc];
                float pw[4] = {pv.x, pv.y, pv.z, pv.w};
#pragma unroll
                for (int w = 0; w < 4; ++w)
#pragma unroll
                    for (int u = 0; u < 4; ++u)
                        acc[i][u] = fmaf(pw[w], sw[w][u], acc[i][u]);
            }
        }
    }
    // store partials
    float* PA = ws + OFF_PACC + ((mh * 2 + b) * LP) * 64;
#pragma unroll
    for (int i = 0; i < 4; ++i) {
        int rl = l0 + 4 * ty + i;
        if (rvalid[i]) {
#pragma unroll
            for (int u = 0; u < 4; ++u) PA[rl * 64 + 4 * tx + u] = acc[i][u];
            if (tx == 0) {
                ws[OFF_PM + (mh * 2 + b) * LP + rl] = mrun[i];
                ws[OFF_PD + (mh * 2 + b) * LP + rl] = drun[i];
            }
        }
    }
}

// ---------------- K3b: merge the two m-halves ----------------
__global__ void k3b_merge(float* __restrict__ ws) {
    int b = blockIdx.y;
    int l = blockIdx.x * 4 + (threadIdx.x >> 6);
    int c = threadIdx.x & 63;
    if (l >= L_) return;
    float m0 = ws[OFF_PM + b * LP + l], m1 = ws[OFF_PM + (2 + b) * LP + l];
    float d0 = ws[OFF_PD + b * LP + l], d1 = ws[OFF_PD + (2 + b) * LP + l];
    float M = fmaxf(m0, m1);
    float w0 = exp2f((m0 - M) * LOG2E), w1 = exp2f((m1 - M) * LOG2E);
    float denom = d0 * w0 + d1 * w1;
    float a0 = ws[OFF_PACC + (b * LP + l) * 64 + c];
    float a1 = ws[OFF_PACC + ((2 + b) * LP + l) * 64 + c];
    ws[OFF_NSTD + (b * LP + l) * 64 + c] = (a0 * w0 + a1 * w1) / denom;
}

// ---------------- K4: fold + affines + compose output ----------------
__global__ void k4_fold(const float* __restrict__ x, const float* __restrict__ mask,
                        const float* __restrict__ fg_g, const float* __restrict__ fg_b,
                        const float* __restrict__ bg_g, const float* __restrict__ bg_b,
                        const float* __restrict__ wsc, float* __restrict__ out) {
    int gid = blockIdx.x * 256 + threadIdx.x;
    int col = gid & 255, r = (gid >> 8) & 255, c = (gid >> 16) & 63, b = gid >> 22;
    float xv = x[gid];
    float m = mask[b * 65536 + r * 256 + col];
    int imin = (r >= 4) ? ((r - 4) >> 2) : 0;
    int imax = min(62, r >> 2);
    int jmin = (col >= 4) ? ((col - 4) >> 2) : 0;
    int jmax = min(62, col >> 2);
    const float* MF = wsc + OFF_MF + (b * 64 + c) * LP;
    const float* SF = wsc + OFF_SF + (b * 64 + c) * LP;
    const float* NS = wsc + OFF_NSTD + b * LP * 64;
    float folded = 0.f;
    int cnt = (imax - imin + 1) * (jmax - jmin + 1);
    for (int i = imin; i <= imax; ++i)
        for (int j = jmin; j <= jmax; ++j) {
            int l = i * 63 + j;
            float mf = MF[l], sf = SF[l];
            float inf_ = (m != 0.f) ? (xv - mf) / sf : mf;
            folded += NS[l * 64 + c] * (inf_ + 1.f);
        }
    float invm = 1.f - m;
    float ub = (xv * invm * (1.f + bg_g[c]) + bg_b[c]) * invm;
    float nf = (folded / (float)cnt * (1.f + fg_g[c]) + fg_b[c]) * m;
    out[gid] = nf + ub;
}

extern "C" void kernel_launch(void* const* d_in, const int* in_sizes, int n_in,
                              void* d_out, int out_size, void* d_ws, size_t ws_size,
                              hipStream_t stream) {
    const float* x    = (const float*)d_in[0];
    const float* mask = (const float*)d_in[1];
    const float* fg_g = (const float*)d_in[2];
    const float* fg_b = (const float*)d_in[3];
    const float* bg_g = (const float*)d_in[4];
    const float* bg_b = (const float*)d_in[5];
    const float* wf   = (const float*)d_in[6];
    const float* wb   = (const float*)d_in[7];
    const float* rpb  = (const float*)d_in[8];
    float* ws = (float*)d_ws;
    float* out = (float*)d_out;

    k0_wt<<<dim3(64, 2), 256, 0, stream>>>(wf, wb, ws);
    k1_stats<<<dim3(63, 64, 2), 256, 0, stream>>>(x, mask, ws);
    hipMemsetAsync(ws + OFF_TOKF, 0, (size_t)(OFF_NSTD - OFF_TOKF) * sizeof(float), stream);
    k2_tok<<<dim3(32, 4, 4), 128, 0, stream>>>(x, mask, ws, ws);
    k3_attn<<<dim3(63, 2, 2), 256, 0, stream>>>(ws, rpb, ws);
    k3b_merge<<<dim3(993, 2), 256, 0, stream>>>(ws);
    k4_fold<<<dim3(32768), 256, 0, stream>>>(x, mask, fg_g, fg_b, bg_g, bg_b, ws, out);
}

// Round 2
// 722.641 us; speedup vs baseline: 1.0323x; 1.0323x over previous
//
#include <hip/hip_runtime.h>
#include <stdint.h>

// Problem constants
#define L_   3969         // patches
#define LP   3972         // padded L (mult of 4, for float4 loads)
#define EPS_ 1e-5f
#define LOG2E 1.4426950408889634f
#define MH   6            // split-m factor in K3
#define MSZ  662          // ceil(L_/MH)

// workspace layout (float offsets). Total 6,720,608 floats = 26.9 MB
#define OFF_MF   0          // [2][64][LP] fg mean
#define OFF_SF   508416     // fg var
#define OFF_MB   1016832    // bg mean
#define OFF_SB   1525248    // bg var
#define OFF_TOKF 2033664    // [2][64][LP]
#define OFF_TOKB 2542080
#define OFF_PACC 3050496    // [MH][2 b][LP][64]; slice p=0 doubles as NSTD after merge
#define OFF_PM   6100992    // [MH][2][LP]
#define OFF_PD   6148656
#define OFF_WT   6196320    // [2 t][64 c][64 k][64 d]

// ---------------- K0: transpose weights to [t][c][k][d] ----------------
__global__ void k0_wt(const float* __restrict__ wf, const float* __restrict__ wb,
                      float* __restrict__ ws) {
    int c = blockIdx.x, t = blockIdx.y;
    const float* w = t ? wb : wf;
    float* wt = ws + OFF_WT + (t * 64 + c) * 4096;
    __shared__ __align__(16) float tile[64][65];
    int k = threadIdx.x & 63, dq = threadIdx.x >> 6;
#pragma unroll
    for (int u = 0; u < 16; ++u) {
        int d = dq * 16 + u;
        tile[d][k] = w[(d * 64 + c) * 64 + k];
    }
    __syncthreads();
    int d2 = threadIdx.x & 63, kq = threadIdx.x >> 6;
#pragma unroll
    for (int u = 0; u < 16; ++u) {
        int kk = kq * 16 + u;
        wt[kk * 64 + d2] = tile[d2][kk];
    }
}

// ---------------- K1: per-patch fg/bg stats ----------------
// grid (63 i, 64 c, 2 b), 256 threads
__global__ void k1_stats(const float* __restrict__ x, const float* __restrict__ mask,
                         float* __restrict__ ws) {
    int i = blockIdx.x, c = blockIdx.y, b = blockIdx.z;
    __shared__ float xs[8 * 256];
    __shared__ float ms[8 * 256];
    __shared__ float pS[5][256];
    int t = threadIdx.x;
    const float* xr = x + (((b * 64 + c) * 256) + i * 4) * 256;
    const float* mr = mask + (b * 256 + i * 4) * 256;
#pragma unroll
    for (int r = 0; r < 8; ++r) {
        xs[r * 256 + t] = xr[r * 256 + t];
        ms[r * 256 + t] = mr[r * 256 + t];
    }
    __syncthreads();
    int q = t >> 6, j = t & 63;
    float Sa = 0, Qa = 0, Sf = 0, Qf = 0, Nf = 0;
    if (j < 63) {
#pragma unroll
        for (int rr = 0; rr < 2; ++rr) {
            int base = (q * 2 + rr) * 256 + j * 4;
#pragma unroll
            for (int cc = 0; cc < 8; ++cc) {
                float v = xs[base + cc], m = ms[base + cc];
                Sa += v; Qa += v * v; Sf += v * m; Qf += v * v * m; Nf += m;
            }
        }
    }
    pS[0][t] = Sa; pS[1][t] = Qa; pS[2][t] = Sf; pS[3][t] = Qf; pS[4][t] = Nf;
    __syncthreads();
    if (q == 0 && j < 63) {
        Sa = pS[0][j] + pS[0][j + 64] + pS[0][j + 128] + pS[0][j + 192];
        Qa = pS[1][j] + pS[1][j + 64] + pS[1][j + 128] + pS[1][j + 192];
        Sf = pS[2][j] + pS[2][j + 64] + pS[2][j + 128] + pS[2][j + 192];
        Qf = pS[3][j] + pS[3][j + 64] + pS[3][j + 128] + pS[3][j + 192];
        Nf = pS[4][j] + pS[4][j + 64] + pS[4][j + 128] + pS[4][j + 192];
        float nb = 64.0f - Nf;
        float muf = Sf / (Nf + EPS_);
        float vaf = (Qf - 2.f * muf * Sf + Nf * muf * muf) / (Nf + EPS_);
        float Sb = Sa - Sf, Qb = Qa - Qf;
        float mub = Sb / (nb + EPS_);
        float vab = (Qb - 2.f * mub * Sb + nb * mub * mub) / (nb + EPS_);
        int idx = (b * 64 + c) * LP + i * 63 + j;
        ws[OFF_MF + idx] = muf; ws[OFF_SF + idx] = vaf;
        ws[OFF_MB + idx] = mub; ws[OFF_SB + idx] = vab;
    }
}

// ---------------- K2: tok GEMM (on-the-fly in_f/in_b), split-K-8 ----------------
// grid (32 lt, 8 kc, 4 t*2+b), 128 threads. 3 blocks/CU (LDS 50 KB).
__global__ __launch_bounds__(128)
void k2_tok(const float* __restrict__ x, const float* __restrict__ mask,
            const float* __restrict__ wsc, float* __restrict__ ws) {
    int lt = blockIdx.x, kc = blockIdx.y;
    int t = blockIdx.z >> 1, b = blockIdx.z & 1;
    int l0 = lt * 128;
    int tid = threadIdx.x;
    __shared__ __align__(16) float wl[64 * 64];     // [k][d]
    __shared__ __align__(16) float inl[64 * 132];   // [k][l]
    const float* MU = wsc + (t ? OFF_MB : OFF_MF);
    const float* VA = wsc + (t ? OFF_SB : OFF_SF);
    const float* WT = wsc + OFF_WT + t * 262144;

    int l = l0 + tid;
    bool valid = l < L_;
    int rowbase = 0;
    uint64_t pmb = 0;
    if (valid) {
        int il = l / 63, jl = l - il * 63;
        rowbase = (il * 4) * 256 + jl * 4;
        const float* mp = mask + b * 65536 + rowbase;
#pragma unroll
        for (int k = 0; k < 64; ++k) {
            if (mp[(k >> 3) * 256 + (k & 7)] != 0.0f) pmb |= (1ull << k);
        }
    }
    if (t) pmb = ~pmb;  // bg: x-side where mask==0

    float acc[8][8];
#pragma unroll
    for (int u = 0; u < 8; ++u)
#pragma unroll
        for (int v = 0; v < 8; ++v) acc[u][v] = 0.f;

    int ty = tid >> 4;  // d-group (8 d)
    int tx = tid & 15;  // l chunks 4tx and 64+4tx

    for (int c = kc * 8; c < kc * 8 + 8; ++c) {
        __syncthreads();
        // build in column (this thread's l)
        {
            float mu = 0.f, inv = 0.f;
            if (valid) {
                mu = MU[(b * 64 + c) * LP + l];
                inv = 1.0f / VA[(b * 64 + c) * LP + l];
            }
            const float* xp = x + (b * 64 + c) * 65536 + rowbase;
#pragma unroll
            for (int k = 0; k < 64; ++k) {
                float in = 0.f;
                if (valid) {
                    float v = xp[(k >> 3) * 256 + (k & 7)];
                    in = ((pmb >> k) & 1) ? (v - mu) * inv : mu;
                }
                inl[k * 132 + tid] = in;
            }
        }
        // stage w tile [k][d]
#pragma unroll
        for (int it = 0; it < 8; ++it) {
            int chunk = it * 128 + tid;
            int k = chunk >> 4, d4 = chunk & 15;
            *(float4*)&wl[k * 64 + d4 * 4] = *(const float4*)&WT[(c * 64 + k) * 64 + d4 * 4];
        }
        __syncthreads();
#pragma unroll 4
        for (int k = 0; k < 64; ++k) {
            float4 A0 = *(const float4*)&wl[k * 64 + 8 * ty];
            float4 A1 = *(const float4*)&wl[k * 64 + 8 * ty + 4];
            float4 B0 = *(const float4*)&inl[k * 132 + 4 * tx];
            float4 B1 = *(const float4*)&inl[k * 132 + 64 + 4 * tx];
            float a[8] = {A0.x, A0.y, A0.z, A0.w, A1.x, A1.y, A1.z, A1.w};
            float bb[8] = {B0.x, B0.y, B0.z, B0.w, B1.x, B1.y, B1.z, B1.w};
#pragma unroll
            for (int u = 0; u < 8; ++u)
#pragma unroll
                for (int v = 0; v < 8; ++v) acc[u][v] = fmaf(a[u], bb[v], acc[u][v]);
        }
    }
    float* tok = ws + (t ? OFF_TOKB : OFF_TOKF) + b * 64 * LP;
#pragma unroll
    for (int u = 0; u < 8; ++u) {
        int d = 8 * ty + u;
#pragma unroll
        for (int v = 0; v < 8; ++v) {
            int ll = (v < 4) ? (4 * tx + v) : (64 + 4 * tx + (v - 4));
            int lg = l0 + ll;
            if (lg < L_) atomicAdd(&tok[d * LP + lg], acc[u][v]);
        }
    }
}

// ---------------- K3: fused logits+bias -> online softmax -> S.sb (split-m-6) ----------------
// grid (63 lt, MH mh, 2 b), 256 threads. LDS 52 KB -> 3 blocks/CU.
__global__ __launch_bounds__(256)
void k3_attn(const float* __restrict__ wsc, const float* __restrict__ rpb,
             float* __restrict__ ws) {
    int lt = blockIdx.x, mh = blockIdx.y, b = blockIdx.z;
    int l0 = lt * 64;
    int mstart = mh * MSZ;
    int mend = min(L_, mstart + MSZ);
    int tid = threadIdx.x;
    int ty = tid >> 4, tx = tid & 15;

    __shared__ __align__(16) float tf[64 * 68];    // [c][l]
    __shared__ __align__(16) float tbp[64 * 68];   // phase1: tb [c][m]; then pL [l][m]
    __shared__ __align__(16) float sbT[64 * 68];   // [m][c]

    const float* TFg = wsc + OFF_TOKF + b * 64 * LP;
    const float* TBg = wsc + OFF_TOKB + b * 64 * LP;
    const float* SBg = wsc + OFF_SB + b * 64 * LP;

#pragma unroll
    for (int it = 0; it < 16; ++it) {
        int e = it * 256 + tid;
        int c = e >> 6, ll = e & 63;
        int lg = l0 + ll;
        tf[c * 68 + ll] = (lg < L_) ? TFg[c * LP + lg] : 0.f;
    }

    int ril[4], rjl[4];
    bool rvalid[4];
#pragma unroll
    for (int i = 0; i < 4; ++i) {
        int rl = l0 + 4 * ty + i;
        rvalid[i] = rl < L_;
        int il = rvalid[i] ? (rl / 63) : 0;
        ril[i] = il; rjl[i] = rvalid[i] ? (rl - il * 63) : 0;
    }
    float mrun[4] = {-1e30f, -1e30f, -1e30f, -1e30f};
    float drun[4] = {0.f, 0.f, 0.f, 0.f};
    float acc[4][4];
#pragma unroll
    for (int i = 0; i < 4; ++i)
#pragma unroll
        for (int u = 0; u < 4; ++u) acc[i][u] = 0.f;

    int nmt = (mend - mstart + 63) >> 6;
    for (int mt = 0; mt < nmt; ++mt) {
        int m0 = mstart + mt * 64;
        __syncthreads();  // previous phase2 done before overwriting tiles
#pragma unroll
        for (int it = 0; it < 16; ++it) {
            int e = it * 256 + tid;
            int c = e >> 6, mm = e & 63;
            int mg = m0 + mm;
            float tv = 0.f, sv = 0.f;
            if (mg < mend) { tv = TBg[c * LP + mg]; sv = SBg[c * LP + mg]; }
            tbp[c * 68 + mm] = tv;
            sbT[mm * 68 + c] = sv;
        }
        __syncthreads();
        // phase1: logits
        float z[4][4];
        int mim[4], mjm[4]; bool mv[4];
#pragma unroll
        for (int j = 0; j < 4; ++j) {
            int mg = m0 + 4 * tx + j;
            mv[j] = mg < mend;
            int im = mv[j] ? (mg / 63) : 0;
            mim[j] = im; mjm[j] = mv[j] ? (mg - im * 63) : 0;
        }
#pragma unroll
        for (int i = 0; i < 4; ++i)
#pragma unroll
            for (int j = 0; j < 4; ++j)
                z[i][j] = (rvalid[i] && mv[j])
                              ? rpb[(ril[i] - mim[j] + 62) * 125 + (rjl[i] - mjm[j] + 62)]
                              : -1e30f;
#pragma unroll 4
        for (int c = 0; c < 64; ++c) {
            float4 av = *(const float4*)&tf[c * 68 + 4 * ty];
            float4 bv = *(const float4*)&tbp[c * 68 + 4 * tx];
            float a[4] = {av.x, av.y, av.z, av.w};
            float bb[4] = {bv.x, bv.y, bv.z, bv.w};
#pragma unroll
            for (int i = 0; i < 4; ++i)
#pragma unroll
                for (int j = 0; j < 4; ++j) z[i][j] = fmaf(a[i], bb[j], z[i][j]);
        }
        // online softmax update
        float p[4][4], mnew[4], alpha[4], rsum[4];
#pragma unroll
        for (int i = 0; i < 4; ++i) {
            float v = fmaxf(fmaxf(z[i][0], z[i][1]), fmaxf(z[i][2], z[i][3]));
            v = fmaxf(v, __shfl_xor(v, 1, 16));
            v = fmaxf(v, __shfl_xor(v, 2, 16));
            v = fmaxf(v, __shfl_xor(v, 4, 16));
            v = fmaxf(v, __shfl_xor(v, 8, 16));
            mnew[i] = fmaxf(mrun[i], v);
            alpha[i] = exp2f((mrun[i] - mnew[i]) * LOG2E);
            float s = 0.f;
#pragma unroll
            for (int j = 0; j < 4; ++j) {
                p[i][j] = exp2f((z[i][j] - mnew[i]) * LOG2E);
                s += p[i][j];
            }
            s += __shfl_xor(s, 1, 16);
            s += __shfl_xor(s, 2, 16);
            s += __shfl_xor(s, 4, 16);
            s += __shfl_xor(s, 8, 16);
            rsum[i] = s;
        }
#pragma unroll
        for (int i = 0; i < 4; ++i) {
            drun[i] = drun[i] * alpha[i] + rsum[i];
            mrun[i] = mnew[i];
#pragma unroll
            for (int u = 0; u < 4; ++u) acc[i][u] *= alpha[i];
        }
        __syncthreads();  // all phase1 tb reads done; tbp becomes pL
#pragma unroll
        for (int i = 0; i < 4; ++i)
            *(float4*)&tbp[(4 * ty + i) * 68 + 4 * tx] =
                make_float4(p[i][0], p[i][1], p[i][2], p[i][3]);
        __syncthreads();
        // phase2: acc[l][c] += p[l][m] * sb[c][m]
#pragma unroll 4
        for (int mc = 0; mc < 16; ++mc) {
            float4 s0 = *(const float4*)&sbT[(4 * mc + 0) * 68 + 4 * tx];
            float4 s1 = *(const float4*)&sbT[(4 * mc + 1) * 68 + 4 * tx];
            float4 s2 = *(const float4*)&sbT[(4 * mc + 2) * 68 + 4 * tx];
            float4 s3 = *(const float4*)&sbT[(4 * mc + 3) * 68 + 4 * tx];
            float sw[4][4] = {{s0.x, s0.y, s0.z, s0.w},
                              {s1.x, s1.y, s1.z, s1.w},
                              {s2.x, s2.y, s2.z, s2.w},
                              {s3.x, s3.y, s3.z, s3.w}};
#pragma unroll
            for (int i = 0; i < 4; ++i) {
                float4 pv = *(const float4*)&tbp[(4 * ty + i) * 68 + 4 * mc];
                float pw[4] = {pv.x, pv.y, pv.z, pv.w};
#pragma unroll
                for (int w = 0; w < 4; ++w)
#pragma unroll
                    for (int u = 0; u < 4; ++u)
                        acc[i][u] = fmaf(pw[w], sw[w][u], acc[i][u]);
            }
        }
    }
    // store partials
    float* PA = ws + OFF_PACC + ((mh * 2 + b) * (size_t)LP) * 64;
#pragma unroll
    for (int i = 0; i < 4; ++i) {
        int rl = l0 + 4 * ty + i;
        if (rvalid[i]) {
#pragma unroll
            for (int u = 0; u < 4; ++u) PA[rl * 64 + 4 * tx + u] = acc[i][u];
            if (tx == 0) {
                ws[OFF_PM + (mh * 2 + b) * LP + rl] = mrun[i];
                ws[OFF_PD + (mh * 2 + b) * LP + rl] = drun[i];
            }
        }
    }
}

// ---------------- K3b: merge the MH m-slices; result lands in PACC slice 0 ----------------
__global__ void k3b_merge(float* __restrict__ ws) {
    int b = blockIdx.y;
    int l = blockIdx.x * 4 + (threadIdx.x >> 6);
    int c = threadIdx.x & 63;
    if (l >= L_) return;
    float M = -1e30f;
#pragma unroll
    for (int p = 0; p < MH; ++p)
        M = fmaxf(M, ws[OFF_PM + (p * 2 + b) * LP + l]);
    float denom = 0.f, num = 0.f;
#pragma unroll
    for (int p = 0; p < MH; ++p) {
        float w = exp2f((ws[OFF_PM + (p * 2 + b) * LP + l] - M) * LOG2E);
        denom += ws[OFF_PD + (p * 2 + b) * LP + l] * w;
        num += ws[OFF_PACC + ((p * 2 + b) * (size_t)LP + l) * 64 + c] * w;
    }
    // write into slice p=0 (aliased as NSTD); safe: this thread is sole owner of (b,l,c)
    ws[OFF_PACC + (b * (size_t)LP + l) * 64 + c] = num / denom;
}

// ---------------- K4: fold + affines + compose output ----------------
__global__ void k4_fold(const float* __restrict__ x, const float* __restrict__ mask,
                        const float* __restrict__ fg_g, const float* __restrict__ fg_b,
                        const float* __restrict__ bg_g, const float* __restrict__ bg_b,
                        const float* __restrict__ wsc, float* __restrict__ out) {
    int gid = blockIdx.x * 256 + threadIdx.x;
    int col = gid & 255, r = (gid >> 8) & 255, c = (gid >> 16) & 63, b = gid >> 22;
    float xv = x[gid];
    float m = mask[b * 65536 + r * 256 + col];
    int imin = (r >= 4) ? ((r - 4) >> 2) : 0;
    int imax = min(62, r >> 2);
    int jmin = (col >= 4) ? ((col - 4) >> 2) : 0;
    int jmax = min(62, col >> 2);
    const float* MF = wsc + OFF_MF + (b * 64 + c) * LP;
    const float* SF = wsc + OFF_SF + (b * 64 + c) * LP;
    const float* NS = wsc + OFF_PACC + b * (size_t)LP * 64;  // merged NSTD (slice 0)
    float folded = 0.f;
    int cnt = (imax - imin + 1) * (jmax - jmin + 1);
    for (int i = imin; i <= imax; ++i)
        for (int j = jmin; j <= jmax; ++j) {
            int l = i * 63 + j;
            float mf = MF[l], sf = SF[l];
            float inf_ = (m != 0.f) ? (xv - mf) / sf : mf;
            folded += NS[l * 64 + c] * (inf_ + 1.f);
        }
    float invm = 1.f - m;
    float ub = (xv * invm * (1.f + bg_g[c]) + bg_b[c]) * invm;
    float nf = (folded / (float)cnt * (1.f + fg_g[c]) + fg_b[c]) * m;
    out[gid] = nf + ub;
}

extern "C" void kernel_launch(void* const* d_in, const int* in_sizes, int n_in,
                              void* d_out, int out_size, void* d_ws, size_t ws_size,
                              hipStream_t stream) {
    const float* x    = (const float*)d_in[0];
    const float* mask = (const float*)d_in[1];
    const float* fg_g = (const float*)d_in[2];
    const float* fg_b = (const float*)d_in[3];
    const float* bg_g = (const float*)d_in[4];
    const float* bg_b = (const float*)d_in[5];
    const float* wf   = (const float*)d_in[6];
    const float* wb   = (const float*)d_in[7];
    const float* rpb  = (const float*)d_in[8];
    float* ws = (float*)d_ws;
    float* out = (float*)d_out;

    k0_wt<<<dim3(64, 2), 256, 0, stream>>>(wf, wb, ws);
    k1_stats<<<dim3(63, 64, 2), 256, 0, stream>>>(x, mask, ws);
    hipMemsetAsync(ws + OFF_TOKF, 0, (size_t)1016832 * sizeof(float), stream);
    k2_tok<<<dim3(32, 8, 4), 128, 0, stream>>>(x, mask, ws, ws);
    k3_attn<<<dim3(63, MH, 2), 256, 0, stream>>>(ws, rpb, ws);
    k3b_merge<<<dim3(993, 2), 256, 0, stream>>>(ws);
    k4_fold<<<dim3(32768), 256, 0, stream>>>(x, mask, fg_g, fg_b, bg_g, bg_b, ws, out);
}

// Round 3
// 503.078 us; speedup vs baseline: 1.4829x; 1.4364x over previous
//
#include <hip/hip_runtime.h>
#include <stdint.h>

// Problem constants
#define L_   3969         // patches
#define LP   3972         // padded L (mult of 4, for float4 loads)
#define EPS_ 1e-5f
#define LOG2E 1.4426950408889634f
#define MH   6            // split-m factor in K3
#define MSZ  662          // ceil(L_/MH)

// workspace layout (float offsets). Total 6,720,608 floats = 26.9 MB
#define OFF_MF   0          // [2][64][LP] fg mean
#define OFF_SF   508416     // fg var
#define OFF_MB   1016832    // bg mean
#define OFF_SB   1525248    // bg var
#define OFF_TOKF 2033664    // [2][64][LP]
#define OFF_TOKB 2542080
#define OFF_PACC 3050496    // [MH][2 b][LP][64]; slice p=0 doubles as NSTD after merge
#define OFF_PM   6100992    // [MH][2][LP]
#define OFF_PD   6148656
#define OFF_WT   6196320    // W2: bf16 frag-ordered weights [t][c][kci][dq][hl][lane][8] (1M bf16)

typedef __attribute__((ext_vector_type(8))) short bf16x8;   // 8 bf16 (4 VGPRs)
typedef __attribute__((ext_vector_type(4))) float f32x4;    // MFMA accumulator

__device__ __forceinline__ uint16_t bf16_rne(float f) {
    uint32_t u = __float_as_uint(f);
    return (uint16_t)((u + 0x7FFFu + ((u >> 16) & 1u)) >> 16);
}
// hi = truncated top-16 bits (exact), lo = RNE(residual): hi+lo ~ 2^-17 relative
__device__ __forceinline__ void split_bf16(float v, uint16_t& h, uint16_t& l) {
    uint32_t u = __float_as_uint(v);
    uint32_t hu = u & 0xFFFF0000u;
    h = (uint16_t)(hu >> 16);
    l = bf16_rne(v - __uint_as_float(hu));
}
__device__ __forceinline__ uint4 pack8(const uint16_t* s) {
    uint4 r;
    r.x = (uint32_t)s[0] | ((uint32_t)s[1] << 16);
    r.y = (uint32_t)s[2] | ((uint32_t)s[3] << 16);
    r.z = (uint32_t)s[4] | ((uint32_t)s[5] << 16);
    r.w = (uint32_t)s[6] | ((uint32_t)s[7] << 16);
    return r;
}

// ---------------- K0: weights -> split-bf16 MFMA A-fragment layout ----------------
// W2[t][c][kci2][dq4][hl2][lane64][8]: lane's A-frag = W[d = dq*16+(lane&15)][k = kci*32+(lane>>4)*8 + j]
__global__ void k0_w2(const float* __restrict__ wf, const float* __restrict__ wb,
                      float* __restrict__ ws) {
    int c = blockIdx.x, t = blockIdx.y;
    const float* w = t ? wb : wf;
    uint16_t* w2 = (uint16_t*)(ws + OFF_WT);
    int tid = threadIdx.x;
    int lane = tid & 63, dq = tid >> 6;
    int d = dq * 16 + (lane & 15), quad = lane >> 4;
    for (int kci = 0; kci < 2; ++kci) {
        int k = kci * 32 + quad * 8;
        const float* src = w + (size_t)(d * 64 + c) * 64 + k;
        uint16_t hb[8], lb[8];
#pragma unroll
        for (int j = 0; j < 8; ++j) split_bf16(src[j], hb[j], lb[j]);
        size_t base = ((size_t)(((t * 64 + c) * 2 + kci) * 4 + dq) * 2) * 512 + lane * 8;
        *(uint4*)(w2 + base) = pack8(hb);
        *(uint4*)(w2 + base + 512) = pack8(lb);
    }
}

// ---------------- K1: per-patch fg/bg stats ----------------
// grid (63 i, 64 c, 2 b), 256 threads
__global__ void k1_stats(const float* __restrict__ x, const float* __restrict__ mask,
                         float* __restrict__ ws) {
    int i = blockIdx.x, c = blockIdx.y, b = blockIdx.z;
    __shared__ float xs[8 * 256];
    __shared__ float ms[8 * 256];
    __shared__ float pS[5][256];
    int t = threadIdx.x;
    const float* xr = x + (((b * 64 + c) * 256) + i * 4) * 256;
    const float* mr = mask + (b * 256 + i * 4) * 256;
#pragma unroll
    for (int r = 0; r < 8; ++r) {
        xs[r * 256 + t] = xr[r * 256 + t];
        ms[r * 256 + t] = mr[r * 256 + t];
    }
    __syncthreads();
    int q = t >> 6, j = t & 63;
    float Sa = 0, Qa = 0, Sf = 0, Qf = 0, Nf = 0;
    if (j < 63) {
#pragma unroll
        for (int rr = 0; rr < 2; ++rr) {
            int base = (q * 2 + rr) * 256 + j * 4;
#pragma unroll
            for (int cc = 0; cc < 8; ++cc) {
                float v = xs[base + cc], m = ms[base + cc];
                Sa += v; Qa += v * v; Sf += v * m; Qf += v * v * m; Nf += m;
            }
        }
    }
    pS[0][t] = Sa; pS[1][t] = Qa; pS[2][t] = Sf; pS[3][t] = Qf; pS[4][t] = Nf;
    __syncthreads();
    if (q == 0 && j < 63) {
        Sa = pS[0][j] + pS[0][j + 64] + pS[0][j + 128] + pS[0][j + 192];
        Qa = pS[1][j] + pS[1][j + 64] + pS[1][j + 128] + pS[1][j + 192];
        Sf = pS[2][j] + pS[2][j + 64] + pS[2][j + 128] + pS[2][j + 192];
        Qf = pS[3][j] + pS[3][j + 64] + pS[3][j + 128] + pS[3][j + 192];
        Nf = pS[4][j] + pS[4][j + 64] + pS[4][j + 128] + pS[4][j + 192];
        float nb = 64.0f - Nf;
        float muf = Sf / (Nf + EPS_);
        float vaf = (Qf - 2.f * muf * Sf + Nf * muf * muf) / (Nf + EPS_);
        float Sb = Sa - Sf, Qb = Qa - Qf;
        float mub = Sb / (nb + EPS_);
        float vab = (Qb - 2.f * mub * Sb + nb * mub * mub) / (nb + EPS_);
        int idx = (b * 64 + c) * LP + i * 63 + j;
        ws[OFF_MF + idx] = muf; ws[OFF_SF + idx] = vaf;
        ws[OFF_MB + idx] = mub; ws[OFF_SB + idx] = vab;
    }
}

// ---------------- K2: split-bf16 MFMA tok GEMM, fg+bg fused, split-K-4 ----------------
// grid (63 il, 4 kc, 2 b), 256 threads. LDS 36 KB -> 4 blocks/CU.
// Block: one patch-row il (63 l, padded to 64 n) x 64 d x both t, c-range 16.
__global__ __launch_bounds__(256)
void k2_tok(const float* __restrict__ x, const float* __restrict__ mask,
            const float* __restrict__ wsc, float* __restrict__ ws) {
    int il = blockIdx.x, kc = blockIdx.y, b = blockIdx.z;
    int tid = threadIdx.x;
    int jl = tid & 63;          // staging: l index; MFMA: lane
    int q = tid >> 6;           // wave id / staging octet group
    __shared__ uint16_t IN[4 * 64 * 72];   // [t*2+hl][l][72] bf16, row stride 72 (2-way only)
    const uint16_t* w2 = (const uint16_t*)(wsc + OFF_WT);

    bool lv = jl < 63;
    int lg = il * 63 + jl;

    // mask bits once per block: rows o=q, q+4 of the patch, this thread's jl
    uint32_t mbits[2] = {0u, 0u};
    if (lv) {
#pragma unroll
        for (int oi = 0; oi < 2; ++oi) {
            int o = q + oi * 4;
            const float* mp = mask + (size_t)b * 65536 + (il * 4 + o) * 256 + jl * 4;
            float4 m0 = *(const float4*)mp;
            float4 m1 = *(const float4*)(mp + 4);
            uint32_t bits = 0;
            bits |= (m0.x != 0.f) ? 1u : 0u;  bits |= (m0.y != 0.f) ? 2u : 0u;
            bits |= (m0.z != 0.f) ? 4u : 0u;  bits |= (m0.w != 0.f) ? 8u : 0u;
            bits |= (m1.x != 0.f) ? 16u : 0u; bits |= (m1.y != 0.f) ? 32u : 0u;
            bits |= (m1.z != 0.f) ? 64u : 0u; bits |= (m1.w != 0.f) ? 128u : 0u;
            mbits[oi] = bits;
        }
    }

    f32x4 acc[2][4];
#pragma unroll
    for (int t = 0; t < 2; ++t)
#pragma unroll
        for (int dq = 0; dq < 4; ++dq) acc[t][dq] = (f32x4)(0.f);

    int lane = tid & 63;
    int quad = lane >> 4;
    int lw = q * 16 + (lane & 15);   // this wave's n-row in LDS

    int c0 = kc * 16;
    for (int ci = 0; ci < 16; ++ci) {
        int c = c0 + ci;
        float muF = 0.f, invF = 0.f, muB = 0.f, invB = 0.f;
        if (lv) {
            int si = (b * 64 + c) * LP + lg;
            muF = wsc[OFF_MF + si]; invF = 1.0f / wsc[OFF_SF + si];
            muB = wsc[OFF_MB + si]; invB = 1.0f / wsc[OFF_SB + si];
        }
        __syncthreads();   // previous MFMA reads done before overwrite
        // ---- stage in_f/in_b hi/lo into LDS (B-fragment layout [l][k]) ----
#pragma unroll
        for (int oi = 0; oi < 2; ++oi) {
            int o = q + oi * 4;
            float xv[8];
            if (lv) {
                const float* xp = x + (size_t)(b * 64 + c) * 65536 + (il * 4 + o) * 256 + jl * 4;
                float4 a0 = *(const float4*)xp;
                float4 a1 = *(const float4*)(xp + 4);
                xv[0] = a0.x; xv[1] = a0.y; xv[2] = a0.z; xv[3] = a0.w;
                xv[4] = a1.x; xv[5] = a1.y; xv[6] = a1.z; xv[7] = a1.w;
            } else {
#pragma unroll
                for (int j = 0; j < 8; ++j) xv[j] = 0.f;
            }
            uint16_t fh[8], fl[8], bh[8], bl[8];
#pragma unroll
            for (int j = 0; j < 8; ++j) {
                float v = xv[j];
                bool mf = (mbits[oi] >> j) & 1;
                float fval = mf ? (v - muF) * invF : muF;
                float bval = mf ? muB : (v - muB) * invB;
                split_bf16(fval, fh[j], fl[j]);
                split_bf16(bval, bh[j], bl[j]);
            }
            uint16_t* p = &IN[jl * 72 + o * 8];
            *(uint4*)(p)         = pack8(fh);   // t=0 hl=0
            *(uint4*)(p + 4608)  = pack8(fl);   // t=0 hl=1
            *(uint4*)(p + 9216)  = pack8(bh);   // t=1 hl=0
            *(uint4*)(p + 13824) = pack8(bl);   // t=1 hl=1
        }
        __syncthreads();
        // ---- MFMA: D[d][l] += W[k][d] * IN[k][l], 3-term split ----
#pragma unroll
        for (int kci = 0; kci < 2; ++kci) {
            bf16x8 Bf[2][2];
#pragma unroll
            for (int t = 0; t < 2; ++t)
#pragma unroll
                for (int hl = 0; hl < 2; ++hl)
                    Bf[t][hl] = *(bf16x8*)&IN[(t * 2 + hl) * 4608 + lw * 72 + kci * 32 + quad * 8];
#pragma unroll
            for (int dq = 0; dq < 4; ++dq) {
#pragma unroll
                for (int t = 0; t < 2; ++t) {
                    const uint16_t* ab =
                        w2 + ((size_t)(((t * 64 + c) * 2 + kci) * 4 + dq) * 2) * 512 + lane * 8;
                    bf16x8 Ah = *(const bf16x8*)ab;
                    bf16x8 Al = *(const bf16x8*)(ab + 512);
                    acc[t][dq] = __builtin_amdgcn_mfma_f32_16x16x32_bf16(Ah, Bf[t][0], acc[t][dq], 0, 0, 0);
                    acc[t][dq] = __builtin_amdgcn_mfma_f32_16x16x32_bf16(Ah, Bf[t][1], acc[t][dq], 0, 0, 0);
                    acc[t][dq] = __builtin_amdgcn_mfma_f32_16x16x32_bf16(Al, Bf[t][0], acc[t][dq], 0, 0, 0);
                }
            }
        }
    }
    // ---- epilogue: C/D layout col(n)=lane&15, row(m)=quad*4+reg ----
    int nl = q * 16 + (lane & 15);
    if (nl < 63) {
        int lg2 = il * 63 + nl;
#pragma unroll
        for (int t = 0; t < 2; ++t) {
            float* tok = ws + (t ? OFF_TOKB : OFF_TOKF) + (size_t)b * 64 * LP;
#pragma unroll
            for (int dq = 0; dq < 4; ++dq)
#pragma unroll
                for (int r = 0; r < 4; ++r)
                    atomicAdd(&tok[(dq * 16 + quad * 4 + r) * LP + lg2], acc[t][dq][r]);
        }
    }
}

// ---------------- K3: fused logits+bias -> online softmax -> S.sb (split-m-6) ----------------
// grid (63 lt, MH mh, 2 b), 256 threads. LDS 52 KB -> 3 blocks/CU.
__global__ __launch_bounds__(256)
void k3_attn(const float* __restrict__ wsc, const float* __restrict__ rpb,
             float* __restrict__ ws) {
    int lt = blockIdx.x, mh = blockIdx.y, b = blockIdx.z;
    int l0 = lt * 64;
    int mstart = mh * MSZ;
    int mend = min(L_, mstart + MSZ);
    int tid = threadIdx.x;
    int ty = tid >> 4, tx = tid & 15;

    __shared__ __align__(16) float tf[64 * 68];    // [c][l]
    __shared__ __align__(16) float tbp[64 * 68];   // phase1: tb [c][m]; then pL [l][m]
    __shared__ __align__(16) float sbT[64 * 68];   // [m][c]

    const float* TFg = wsc + OFF_TOKF + b * 64 * LP;
    const float* TBg = wsc + OFF_TOKB + b * 64 * LP;
    const float* SBg = wsc + OFF_SB + b * 64 * LP;

#pragma unroll
    for (int it = 0; it < 16; ++it) {
        int e = it * 256 + tid;
        int c = e >> 6, ll = e & 63;
        int lg = l0 + ll;
        tf[c * 68 + ll] = (lg < L_) ? TFg[c * LP + lg] : 0.f;
    }

    int ril[4], rjl[4];
    bool rvalid[4];
#pragma unroll
    for (int i = 0; i < 4; ++i) {
        int rl = l0 + 4 * ty + i;
        rvalid[i] = rl < L_;
        int il = rvalid[i] ? (rl / 63) : 0;
        ril[i] = il; rjl[i] = rvalid[i] ? (rl - il * 63) : 0;
    }
    float mrun[4] = {-1e30f, -1e30f, -1e30f, -1e30f};
    float drun[4] = {0.f, 0.f, 0.f, 0.f};
    float acc[4][4];
#pragma unroll
    for (int i = 0; i < 4; ++i)
#pragma unroll
        for (int u = 0; u < 4; ++u) acc[i][u] = 0.f;

    int nmt = (mend - mstart + 63) >> 6;
    for (int mt = 0; mt < nmt; ++mt) {
        int m0 = mstart + mt * 64;
        __syncthreads();  // previous phase2 done before overwriting tiles
#pragma unroll
        for (int it = 0; it < 16; ++it) {
            int e = it * 256 + tid;
            int c = e >> 6, mm = e & 63;
            int mg = m0 + mm;
            float tv = 0.f, sv = 0.f;
            if (mg < mend) { tv = TBg[c * LP + mg]; sv = SBg[c * LP + mg]; }
            tbp[c * 68 + mm] = tv;
            sbT[mm * 68 + c] = sv;
        }
        __syncthreads();
        // phase1: logits
        float z[4][4];
        int mim[4], mjm[4]; bool mv[4];
#pragma unroll
        for (int j = 0; j < 4; ++j) {
            int mg = m0 + 4 * tx + j;
            mv[j] = mg < mend;
            int im = mv[j] ? (mg / 63) : 0;
            mim[j] = im; mjm[j] = mv[j] ? (mg - im * 63) : 0;
        }
#pragma unroll
        for (int i = 0; i < 4; ++i)
#pragma unroll
            for (int j = 0; j < 4; ++j)
                z[i][j] = (rvalid[i] && mv[j])
                              ? rpb[(ril[i] - mim[j] + 62) * 125 + (rjl[i] - mjm[j] + 62)]
                              : -1e30f;
#pragma unroll 4
        for (int c = 0; c < 64; ++c) {
            float4 av = *(const float4*)&tf[c * 68 + 4 * ty];
            float4 bv = *(const float4*)&tbp[c * 68 + 4 * tx];
            float a[4] = {av.x, av.y, av.z, av.w};
            float bb[4] = {bv.x, bv.y, bv.z, bv.w};
#pragma unroll
            for (int i = 0; i < 4; ++i)
#pragma unroll
                for (int j = 0; j < 4; ++j) z[i][j] = fmaf(a[i], bb[j], z[i][j]);
        }
        // online softmax update
        float p[4][4], mnew[4], alpha[4], rsum[4];
#pragma unroll
        for (int i = 0; i < 4; ++i) {
            float v = fmaxf(fmaxf(z[i][0], z[i][1]), fmaxf(z[i][2], z[i][3]));
            v = fmaxf(v, __shfl_xor(v, 1, 16));
            v = fmaxf(v, __shfl_xor(v, 2, 16));
            v = fmaxf(v, __shfl_xor(v, 4, 16));
            v = fmaxf(v, __shfl_xor(v, 8, 16));
            mnew[i] = fmaxf(mrun[i], v);
            alpha[i] = exp2f((mrun[i] - mnew[i]) * LOG2E);
            float s = 0.f;
#pragma unroll
            for (int j = 0; j < 4; ++j) {
                p[i][j] = exp2f((z[i][j] - mnew[i]) * LOG2E);
                s += p[i][j];
            }
            s += __shfl_xor(s, 1, 16);
            s += __shfl_xor(s, 2, 16);
            s += __shfl_xor(s, 4, 16);
            s += __shfl_xor(s, 8, 16);
            rsum[i] = s;
        }
#pragma unroll
        for (int i = 0; i < 4; ++i) {
            drun[i] = drun[i] * alpha[i] + rsum[i];
            mrun[i] = mnew[i];
#pragma unroll
            for (int u = 0; u < 4; ++u) acc[i][u] *= alpha[i];
        }
        __syncthreads();  // all phase1 tb reads done; tbp becomes pL
#pragma unroll
        for (int i = 0; i < 4; ++i)
            *(float4*)&tbp[(4 * ty + i) * 68 + 4 * tx] =
                make_float4(p[i][0], p[i][1], p[i][2], p[i][3]);
        __syncthreads();
        // phase2: acc[l][c] += p[l][m] * sb[c][m]
#pragma unroll 4
        for (int mc = 0; mc < 16; ++mc) {
            float4 s0 = *(const float4*)&sbT[(4 * mc + 0) * 68 + 4 * tx];
            float4 s1 = *(const float4*)&sbT[(4 * mc + 1) * 68 + 4 * tx];
            float4 s2 = *(const float4*)&sbT[(4 * mc + 2) * 68 + 4 * tx];
            float4 s3 = *(const float4*)&sbT[(4 * mc + 3) * 68 + 4 * tx];
            float sw[4][4] = {{s0.x, s0.y, s0.z, s0.w},
                              {s1.x, s1.y, s1.z, s1.w},
                              {s2.x, s2.y, s2.z, s2.w},
                              {s3.x, s3.y, s3.z, s3.w}};
#pragma unroll
            for (int i = 0; i < 4; ++i) {
                float4 pv = *(const float4*)&tbp[(4 * ty + i) * 68 + 4 * mc];
                float pw[4] = {pv.x, pv.y, pv.z, pv.w};
#pragma unroll
                for (int w = 0; w < 4; ++w)
#pragma unroll
                    for (int u = 0; u < 4; ++u)
                        acc[i][u] = fmaf(pw[w], sw[w][u], acc[i][u]);
            }
        }
    }
    // store partials
    float* PA = ws + OFF_PACC + ((mh * 2 + b) * (size_t)LP) * 64;
#pragma unroll
    for (int i = 0; i < 4; ++i) {
        int rl = l0 + 4 * ty + i;
        if (rvalid[i]) {
#pragma unroll
            for (int u = 0; u < 4; ++u) PA[rl * 64 + 4 * tx + u] = acc[i][u];
            if (tx == 0) {
                ws[OFF_PM + (mh * 2 + b) * LP + rl] = mrun[i];
                ws[OFF_PD + (mh * 2 + b) * LP + rl] = drun[i];
            }
        }
    }
}

// ---------------- K3b: merge the MH m-slices; result lands in PACC slice 0 ----------------
__global__ void k3b_merge(float* __restrict__ ws) {
    int b = blockIdx.y;
    int l = blockIdx.x * 4 + (threadIdx.x >> 6);
    int c = threadIdx.x & 63;
    if (l >= L_) return;
    float M = -1e30f;
#pragma unroll
    for (int p = 0; p < MH; ++p)
        M = fmaxf(M, ws[OFF_PM + (p * 2 + b) * LP + l]);
    float denom = 0.f, num = 0.f;
#pragma unroll
    for (int p = 0; p < MH; ++p) {
        float w = exp2f((ws[OFF_PM + (p * 2 + b) * LP + l] - M) * LOG2E);
        denom += ws[OFF_PD + (p * 2 + b) * LP + l] * w;
        num += ws[OFF_PACC + ((p * 2 + b) * (size_t)LP + l) * 64 + c] * w;
    }
    ws[OFF_PACC + (b * (size_t)LP + l) * 64 + c] = num / denom;
}

// ---------------- K4: fold + affines + compose output ----------------
__global__ void k4_fold(const float* __restrict__ x, const float* __restrict__ mask,
                        const float* __restrict__ fg_g, const float* __restrict__ fg_b,
                        const float* __restrict__ bg_g, const float* __restrict__ bg_b,
                        const float* __restrict__ wsc, float* __restrict__ out) {
    int gid = blockIdx.x * 256 + threadIdx.x;
    int col = gid & 255, r = (gid >> 8) & 255, c = (gid >> 16) & 63, b = gid >> 22;
    float xv = x[gid];
    float m = mask[b * 65536 + r * 256 + col];
    int imin = (r >= 4) ? ((r - 4) >> 2) : 0;
    int imax = min(62, r >> 2);
    int jmin = (col >= 4) ? ((col - 4) >> 2) : 0;
    int jmax = min(62, col >> 2);
    const float* MF = wsc + OFF_MF + (b * 64 + c) * LP;
    const float* SF = wsc + OFF_SF + (b * 64 + c) * LP;
    const float* NS = wsc + OFF_PACC + b * (size_t)LP * 64;  // merged NSTD (slice 0)
    float folded = 0.f;
    int cnt = (imax - imin + 1) * (jmax - jmin + 1);
    for (int i = imin; i <= imax; ++i)
        for (int j = jmin; j <= jmax; ++j) {
            int l = i * 63 + j;
            float mf = MF[l], sf = SF[l];
            float inf_ = (m != 0.f) ? (xv - mf) / sf : mf;
            folded += NS[l * 64 + c] * (inf_ + 1.f);
        }
    float invm = 1.f - m;
    float ub = (xv * invm * (1.f + bg_g[c]) + bg_b[c]) * invm;
    float nf = (folded / (float)cnt * (1.f + fg_g[c]) + fg_b[c]) * m;
    out[gid] = nf + ub;
}

extern "C" void kernel_launch(void* const* d_in, const int* in_sizes, int n_in,
                              void* d_out, int out_size, void* d_ws, size_t ws_size,
                              hipStream_t stream) {
    const float* x    = (const float*)d_in[0];
    const float* mask = (const float*)d_in[1];
    const float* fg_g = (const float*)d_in[2];
    const float* fg_b = (const float*)d_in[3];
    const float* bg_g = (const float*)d_in[4];
    const float* bg_b = (const float*)d_in[5];
    const float* wf   = (const float*)d_in[6];
    const float* wb   = (const float*)d_in[7];
    const float* rpb  = (const float*)d_in[8];
    float* ws = (float*)d_ws;
    float* out = (float*)d_out;

    k0_w2<<<dim3(64, 2), 256, 0, stream>>>(wf, wb, ws);
    k1_stats<<<dim3(63, 64, 2), 256, 0, stream>>>(x, mask, ws);
    hipMemsetAsync(ws + OFF_TOKF, 0, (size_t)1016832 * sizeof(float), stream);
    k2_tok<<<dim3(63, 4, 2), 256, 0, stream>>>(x, mask, ws, ws);
    k3_attn<<<dim3(63, MH, 2), 256, 0, stream>>>(ws, rpb, ws);
    k3b_merge<<<dim3(993, 2), 256, 0, stream>>>(ws);
    k4_fold<<<dim3(32768), 256, 0, stream>>>(x, mask, fg_g, fg_b, bg_g, bg_b, ws, out);
}

// Round 4
// 382.518 us; speedup vs baseline: 1.9503x; 1.3152x over previous
//
#include <hip/hip_runtime.h>
#include <stdint.h>

// Problem constants
#define L_   3969         // patches
#define LP   3972         // padded L (mult of 4, for float4 loads)
#define EPS_ 1e-5f
#define LOG2E 1.4426950408889634f
#define MH   6            // split over im (patch-row chunks) in K3
#define IMR  11           // im rows per chunk (6*11 >= 63)

// workspace layout (float offsets). Total 6,720,608 floats = 26.9 MB
#define OFF_MF   0          // [2][64][LP] fg mean
#define OFF_SF   508416     // fg var
#define OFF_MB   1016832    // bg mean
#define OFF_SB   1525248    // bg var
#define OFF_TOKF 2033664    // [2 b][LP][64 c]  (l-major rows, 256B aligned)
#define OFF_TOKB 2542080
#define OFF_PACC 3050496    // [MH][2 b][LP][64]; slice p=0 doubles as NSTD after merge
#define OFF_PM   6100992    // [MH][2][LP]
#define OFF_PD   6148656
#define OFF_WT   6196320    // W2: bf16 frag-ordered weights [t][c][kci][dq][hl][lane][8] (1M bf16)

typedef __attribute__((ext_vector_type(8))) short bf16x8;   // 8 bf16 (4 VGPRs)
typedef __attribute__((ext_vector_type(4))) float f32x4;    // MFMA accumulator

__device__ __forceinline__ uint16_t bf16_rne(float f) {
    uint32_t u = __float_as_uint(f);
    return (uint16_t)((u + 0x7FFFu + ((u >> 16) & 1u)) >> 16);
}
// hi = truncated top-16 bits (exact), lo = RNE(residual): hi+lo ~ 2^-17 relative
__device__ __forceinline__ void split_bf16(float v, uint16_t& h, uint16_t& l) {
    uint32_t u = __float_as_uint(v);
    uint32_t hu = u & 0xFFFF0000u;
    h = (uint16_t)(hu >> 16);
    l = bf16_rne(v - __uint_as_float(hu));
}
__device__ __forceinline__ uint4 pack8(const uint16_t* s) {
    uint4 r;
    r.x = (uint32_t)s[0] | ((uint32_t)s[1] << 16);
    r.y = (uint32_t)s[2] | ((uint32_t)s[3] << 16);
    r.z = (uint32_t)s[4] | ((uint32_t)s[5] << 16);
    r.w = (uint32_t)s[6] | ((uint32_t)s[7] << 16);
    return r;
}

// ---------------- K0: weights -> split-bf16 MFMA A-fragment layout ----------------
__global__ void k0_w2(const float* __restrict__ wf, const float* __restrict__ wb,
                      float* __restrict__ ws) {
    int c = blockIdx.x, t = blockIdx.y;
    const float* w = t ? wb : wf;
    uint16_t* w2 = (uint16_t*)(ws + OFF_WT);
    int tid = threadIdx.x;
    int lane = tid & 63, dq = tid >> 6;
    int d = dq * 16 + (lane & 15), quad = lane >> 4;
    for (int kci = 0; kci < 2; ++kci) {
        int k = kci * 32 + quad * 8;
        const float* src = w + (size_t)(d * 64 + c) * 64 + k;
        uint16_t hb[8], lb[8];
#pragma unroll
        for (int j = 0; j < 8; ++j) split_bf16(src[j], hb[j], lb[j]);
        size_t base = ((size_t)(((t * 64 + c) * 2 + kci) * 4 + dq) * 2) * 512 + lane * 8;
        *(uint4*)(w2 + base) = pack8(hb);
        *(uint4*)(w2 + base + 512) = pack8(lb);
    }
}

// ---------------- K1: per-patch fg/bg stats ----------------
__global__ void k1_stats(const float* __restrict__ x, const float* __restrict__ mask,
                         float* __restrict__ ws) {
    int i = blockIdx.x, c = blockIdx.y, b = blockIdx.z;
    __shared__ float xs[8 * 256];
    __shared__ float ms[8 * 256];
    __shared__ float pS[5][256];
    int t = threadIdx.x;
    const float* xr = x + (((b * 64 + c) * 256) + i * 4) * 256;
    const float* mr = mask + (b * 256 + i * 4) * 256;
#pragma unroll
    for (int r = 0; r < 8; ++r) {
        xs[r * 256 + t] = xr[r * 256 + t];
        ms[r * 256 + t] = mr[r * 256 + t];
    }
    __syncthreads();
    int q = t >> 6, j = t & 63;
    float Sa = 0, Qa = 0, Sf = 0, Qf = 0, Nf = 0;
    if (j < 63) {
#pragma unroll
        for (int rr = 0; rr < 2; ++rr) {
            int base = (q * 2 + rr) * 256 + j * 4;
#pragma unroll
            for (int cc = 0; cc < 8; ++cc) {
                float v = xs[base + cc], m = ms[base + cc];
                Sa += v; Qa += v * v; Sf += v * m; Qf += v * v * m; Nf += m;
            }
        }
    }
    pS[0][t] = Sa; pS[1][t] = Qa; pS[2][t] = Sf; pS[3][t] = Qf; pS[4][t] = Nf;
    __syncthreads();
    if (q == 0 && j < 63) {
        Sa = pS[0][j] + pS[0][j + 64] + pS[0][j + 128] + pS[0][j + 192];
        Qa = pS[1][j] + pS[1][j + 64] + pS[1][j + 128] + pS[1][j + 192];
        Sf = pS[2][j] + pS[2][j + 64] + pS[2][j + 128] + pS[2][j + 192];
        Qf = pS[3][j] + pS[3][j + 64] + pS[3][j + 128] + pS[3][j + 192];
        Nf = pS[4][j] + pS[4][j + 64] + pS[4][j + 128] + pS[4][j + 192];
        float nb = 64.0f - Nf;
        float muf = Sf / (Nf + EPS_);
        float vaf = (Qf - 2.f * muf * Sf + Nf * muf * muf) / (Nf + EPS_);
        float Sb = Sa - Sf, Qb = Qa - Qf;
        float mub = Sb / (nb + EPS_);
        float vab = (Qb - 2.f * mub * Sb + nb * mub * mub) / (nb + EPS_);
        int idx = (b * 64 + c) * LP + i * 63 + j;
        ws[OFF_MF + idx] = muf; ws[OFF_SF + idx] = vaf;
        ws[OFF_MB + idx] = mub; ws[OFF_SB + idx] = vab;
    }
}

// ---------------- K2: split-bf16 MFMA tok GEMM, fg+bg fused, split-K-4 ----------------
// grid (63 il, 4 kc, 2 b), 256 threads. tok output now [b][l][c] (l-major).
__global__ __launch_bounds__(256)
void k2_tok(const float* __restrict__ x, const float* __restrict__ mask,
            const float* __restrict__ wsc, float* __restrict__ ws) {
    int il = blockIdx.x, kc = blockIdx.y, b = blockIdx.z;
    int tid = threadIdx.x;
    int jl = tid & 63;
    int q = tid >> 6;
    __shared__ uint16_t IN[4 * 64 * 72];   // [t*2+hl][l][72]
    const uint16_t* w2 = (const uint16_t*)(wsc + OFF_WT);

    bool lv = jl < 63;
    int lg = il * 63 + jl;

    uint32_t mbits[2] = {0u, 0u};
    if (lv) {
#pragma unroll
        for (int oi = 0; oi < 2; ++oi) {
            int o = q + oi * 4;
            const float* mp = mask + (size_t)b * 65536 + (il * 4 + o) * 256 + jl * 4;
            float4 m0 = *(const float4*)mp;
            float4 m1 = *(const float4*)(mp + 4);
            uint32_t bits = 0;
            bits |= (m0.x != 0.f) ? 1u : 0u;  bits |= (m0.y != 0.f) ? 2u : 0u;
            bits |= (m0.z != 0.f) ? 4u : 0u;  bits |= (m0.w != 0.f) ? 8u : 0u;
            bits |= (m1.x != 0.f) ? 16u : 0u; bits |= (m1.y != 0.f) ? 32u : 0u;
            bits |= (m1.z != 0.f) ? 64u : 0u; bits |= (m1.w != 0.f) ? 128u : 0u;
            mbits[oi] = bits;
        }
    }

    f32x4 acc[2][4];
#pragma unroll
    for (int t = 0; t < 2; ++t)
#pragma unroll
        for (int dq = 0; dq < 4; ++dq) acc[t][dq] = (f32x4)(0.f);

    int lane = tid & 63;
    int quad = lane >> 4;
    int lw = q * 16 + (lane & 15);

    int c0 = kc * 16;
    for (int ci = 0; ci < 16; ++ci) {
        int c = c0 + ci;
        float muF = 0.f, invF = 0.f, muB = 0.f, invB = 0.f;
        if (lv) {
            int si = (b * 64 + c) * LP + lg;
            muF = wsc[OFF_MF + si]; invF = 1.0f / wsc[OFF_SF + si];
            muB = wsc[OFF_MB + si]; invB = 1.0f / wsc[OFF_SB + si];
        }
        __syncthreads();
#pragma unroll
        for (int oi = 0; oi < 2; ++oi) {
            int o = q + oi * 4;
            float xv[8];
            if (lv) {
                const float* xp = x + (size_t)(b * 64 + c) * 65536 + (il * 4 + o) * 256 + jl * 4;
                float4 a0 = *(const float4*)xp;
                float4 a1 = *(const float4*)(xp + 4);
                xv[0] = a0.x; xv[1] = a0.y; xv[2] = a0.z; xv[3] = a0.w;
                xv[4] = a1.x; xv[5] = a1.y; xv[6] = a1.z; xv[7] = a1.w;
            } else {
#pragma unroll
                for (int j = 0; j < 8; ++j) xv[j] = 0.f;
            }
            uint16_t fh[8], fl[8], bh[8], bl[8];
#pragma unroll
            for (int j = 0; j < 8; ++j) {
                float v = xv[j];
                bool mf = (mbits[oi] >> j) & 1;
                float fval = mf ? (v - muF) * invF : muF;
                float bval = mf ? muB : (v - muB) * invB;
                split_bf16(fval, fh[j], fl[j]);
                split_bf16(bval, bh[j], bl[j]);
            }
            uint16_t* p = &IN[jl * 72 + o * 8];
            *(uint4*)(p)         = pack8(fh);
            *(uint4*)(p + 4608)  = pack8(fl);
            *(uint4*)(p + 9216)  = pack8(bh);
            *(uint4*)(p + 13824) = pack8(bl);
        }
        __syncthreads();
#pragma unroll
        for (int kci = 0; kci < 2; ++kci) {
            bf16x8 Bf[2][2];
#pragma unroll
            for (int t = 0; t < 2; ++t)
#pragma unroll
                for (int hl = 0; hl < 2; ++hl)
                    Bf[t][hl] = *(bf16x8*)&IN[(t * 2 + hl) * 4608 + lw * 72 + kci * 32 + quad * 8];
#pragma unroll
            for (int dq = 0; dq < 4; ++dq) {
#pragma unroll
                for (int t = 0; t < 2; ++t) {
                    const uint16_t* ab =
                        w2 + ((size_t)(((t * 64 + c) * 2 + kci) * 4 + dq) * 2) * 512 + lane * 8;
                    bf16x8 Ah = *(const bf16x8*)ab;
                    bf16x8 Al = *(const bf16x8*)(ab + 512);
                    acc[t][dq] = __builtin_amdgcn_mfma_f32_16x16x32_bf16(Ah, Bf[t][0], acc[t][dq], 0, 0, 0);
                    acc[t][dq] = __builtin_amdgcn_mfma_f32_16x16x32_bf16(Ah, Bf[t][1], acc[t][dq], 0, 0, 0);
                    acc[t][dq] = __builtin_amdgcn_mfma_f32_16x16x32_bf16(Al, Bf[t][0], acc[t][dq], 0, 0, 0);
                }
            }
        }
    }
    // epilogue: C/D row(d)=quad*4+reg (+dq*16), col(l)=lane&15 (+q*16); tok is [l][c]
    int nl = q * 16 + (lane & 15);
    if (nl < 63) {
        int lg2 = il * 63 + nl;
#pragma unroll
        for (int t = 0; t < 2; ++t) {
            float* tok = ws + (t ? OFF_TOKB : OFF_TOKF) + (size_t)b * LP * 64;
#pragma unroll
            for (int dq = 0; dq < 4; ++dq)
#pragma unroll
                for (int r = 0; r < 4; ++r)
                    atomicAdd(&tok[(size_t)lg2 * 64 + dq * 16 + quad * 4 + r], acc[t][dq][r]);
        }
    }
}

// ---------------- K3: MFMA flash attention over patch-rows ----------------
// grid (63 il, MH imc, 2 b), 256 threads. Q-tile = one il row (63 l), K-tiles = im rows.
// Bias per (il,im) is ONE rpb row of 125 entries -> LDS lookup.
__global__ __launch_bounds__(256)
void k3_attn(const float* __restrict__ wsc, const float* __restrict__ rpb,
             float* __restrict__ ws) {
    int il = blockIdx.x, imc = blockIdx.y, b = blockIdx.z;
    int tid = threadIdx.x;
    int w = tid >> 6, lane = tid & 63;
    int c16 = lane & 15, quad = lane >> 4;

    __shared__ uint16_t TFh[64 * 72], TFl[64 * 72];   // tok_f [l][c] hi/lo
    __shared__ uint16_t TBh[64 * 72];                 // tok_b hi [m][c]; aliased as P [l][m]
    __shared__ uint16_t TBl[64 * 72];                 // tok_b lo
    __shared__ uint16_t SB[64 * 72];                  // sb [c][m] bf16
    __shared__ float bias_r[128];

    const float* TOKF = wsc + OFF_TOKF + (size_t)b * LP * 64;
    const float* TOKB = wsc + OFF_TOKB + (size_t)b * LP * 64;
    const float* SBg  = wsc + OFF_SB + (size_t)b * 64 * LP;   // [c][LP]

    // stage TF (once per block): rows jl, split hi/lo
    {
        int jl = tid >> 2, cc = (tid & 3) * 16;
        bool v = jl < 63;
        const float* src = TOKF + (size_t)(il * 63 + jl) * 64 + cc;
        uint16_t hh[16], lo[16];
#pragma unroll
        for (int u = 0; u < 16; u += 4) {
            float4 f = v ? *(const float4*)(src + u) : make_float4(0.f, 0.f, 0.f, 0.f);
            split_bf16(f.x, hh[u], lo[u]);     split_bf16(f.y, hh[u + 1], lo[u + 1]);
            split_bf16(f.z, hh[u + 2], lo[u + 2]); split_bf16(f.w, hh[u + 3], lo[u + 3]);
        }
        *(uint4*)&TFh[jl * 72 + cc] = pack8(hh); *(uint4*)&TFh[jl * 72 + cc + 8] = pack8(hh + 8);
        *(uint4*)&TFl[jl * 72 + cc] = pack8(lo); *(uint4*)&TFl[jl * 72 + cc + 8] = pack8(lo + 8);
    }

    float mrun[4] = {-1e30f, -1e30f, -1e30f, -1e30f};
    float drun[4] = {0.f, 0.f, 0.f, 0.f};
    f32x4 acc2[4];
#pragma unroll
    for (int ct = 0; ct < 4; ++ct) acc2[ct] = (f32x4)(0.f);

    int im0 = imc * IMR;
    int im1 = min(63, im0 + IMR);
    for (int im = im0; im < im1; ++im) {
        __syncthreads();   // prev phase2 reads (P, SB) done
        // stage TB rows jm (hi/lo)
        {
            int jm = tid >> 2, cc = (tid & 3) * 16;
            bool v = jm < 63;
            const float* src = TOKB + (size_t)(im * 63 + jm) * 64 + cc;
            uint16_t hh[16], lo[16];
#pragma unroll
            for (int u = 0; u < 16; u += 4) {
                float4 f = v ? *(const float4*)(src + u) : make_float4(0.f, 0.f, 0.f, 0.f);
                split_bf16(f.x, hh[u], lo[u]);     split_bf16(f.y, hh[u + 1], lo[u + 1]);
                split_bf16(f.z, hh[u + 2], lo[u + 2]); split_bf16(f.w, hh[u + 3], lo[u + 3]);
            }
            *(uint4*)&TBh[jm * 72 + cc] = pack8(hh); *(uint4*)&TBh[jm * 72 + cc + 8] = pack8(hh + 8);
            *(uint4*)&TBl[jm * 72 + cc] = pack8(lo); *(uint4*)&TBl[jm * 72 + cc + 8] = pack8(lo + 8);
        }
        // stage SB [c][m] bf16 (scalar loads: row base not 16B aligned)
        {
            int c = tid >> 2, mm = (tid & 3) * 16;
            const float* src = SBg + (size_t)c * LP + im * 63 + mm;
            uint16_t sv[16];
#pragma unroll
            for (int u = 0; u < 16; ++u)
                sv[u] = (mm + u < 63) ? bf16_rne(src[u]) : (uint16_t)0;
            *(uint4*)&SB[c * 72 + mm] = pack8(sv); *(uint4*)&SB[c * 72 + mm + 8] = pack8(sv + 8);
        }
        if (tid < 125) bias_r[tid] = rpb[(il - im + 62) * 125 + tid];
        else if (tid < 128) bias_r[tid] = 0.f;
        __syncthreads();

        // phase1: Z[l][m] = tf.tb (3-term split bf16)
        f32x4 Z[4];
#pragma unroll
        for (int jt = 0; jt < 4; ++jt) Z[jt] = (f32x4)(0.f);
#pragma unroll
        for (int kk = 0; kk < 2; ++kk) {
            bf16x8 Ah = *(bf16x8*)&TFh[(w * 16 + c16) * 72 + kk * 32 + quad * 8];
            bf16x8 Al = *(bf16x8*)&TFl[(w * 16 + c16) * 72 + kk * 32 + quad * 8];
#pragma unroll
            for (int jt = 0; jt < 4; ++jt) {
                bf16x8 Bh = *(bf16x8*)&TBh[(jt * 16 + c16) * 72 + kk * 32 + quad * 8];
                bf16x8 Bl = *(bf16x8*)&TBl[(jt * 16 + c16) * 72 + kk * 32 + quad * 8];
                Z[jt] = __builtin_amdgcn_mfma_f32_16x16x32_bf16(Ah, Bh, Z[jt], 0, 0, 0);
                Z[jt] = __builtin_amdgcn_mfma_f32_16x16x32_bf16(Ah, Bl, Z[jt], 0, 0, 0);
                Z[jt] = __builtin_amdgcn_mfma_f32_16x16x32_bf16(Al, Bh, Z[jt], 0, 0, 0);
            }
        }
        // bias + online softmax. Row i = w*16+quad*4+r, col jm = jt*16+c16.
        float zv[4][4];
#pragma unroll
        for (int jt = 0; jt < 4; ++jt) {
            int jm = jt * 16 + c16;
#pragma unroll
            for (int r = 0; r < 4; ++r) {
                int i = w * 16 + quad * 4 + r;
                zv[jt][r] = (jm == 63) ? -1e30f : (Z[jt][r] + bias_r[i - jm + 62]);
            }
        }
        float alphav[4];
        uint16_t pb[4][4];
#pragma unroll
        for (int r = 0; r < 4; ++r) {
            float v = fmaxf(fmaxf(zv[0][r], zv[1][r]), fmaxf(zv[2][r], zv[3][r]));
            v = fmaxf(v, __shfl_xor(v, 1));
            v = fmaxf(v, __shfl_xor(v, 2));
            v = fmaxf(v, __shfl_xor(v, 4));
            v = fmaxf(v, __shfl_xor(v, 8));
            float mnew = fmaxf(mrun[r], v);
            alphav[r] = exp2f((mrun[r] - mnew) * LOG2E);
            float s = 0.f;
#pragma unroll
            for (int jt = 0; jt < 4; ++jt) {
                float p = exp2f((zv[jt][r] - mnew) * LOG2E);
                uint16_t h = bf16_rne(p);
                pb[jt][r] = h;
                s += __uint_as_float((uint32_t)h << 16);   // sum ROUNDED p -> consistent denom
            }
            s += __shfl_xor(s, 1); s += __shfl_xor(s, 2);
            s += __shfl_xor(s, 4); s += __shfl_xor(s, 8);
            drun[r] = drun[r] * alphav[r] + s;
            mrun[r] = mnew;
        }
#pragma unroll
        for (int ct = 0; ct < 4; ++ct)
#pragma unroll
            for (int r = 0; r < 4; ++r) acc2[ct][r] *= alphav[r];

        __syncthreads();   // phase1 TBh reads done; TBh becomes P [l][m]
#pragma unroll
        for (int jt = 0; jt < 4; ++jt)
#pragma unroll
            for (int r = 0; r < 4; ++r)
                TBh[(w * 16 + quad * 4 + r) * 72 + jt * 16 + c16] = pb[jt][r];
        __syncthreads();

        // phase2: acc2[l][c] += P[l][m] * sb[c][m]
#pragma unroll
        for (int kk = 0; kk < 2; ++kk) {
            bf16x8 Pf = *(bf16x8*)&TBh[(w * 16 + c16) * 72 + kk * 32 + quad * 8];
#pragma unroll
            for (int ct = 0; ct < 4; ++ct) {
                bf16x8 Sf = *(bf16x8*)&SB[(ct * 16 + c16) * 72 + kk * 32 + quad * 8];
                acc2[ct] = __builtin_amdgcn_mfma_f32_16x16x32_bf16(Pf, Sf, acc2[ct], 0, 0, 0);
            }
        }
    }
    // store partials: D row(l)=w*16+quad*4+r, col(c)=ct*16+c16
    float* PA = ws + OFF_PACC + ((imc * 2 + b) * (size_t)LP) * 64;
#pragma unroll
    for (int r = 0; r < 4; ++r) {
        int i = w * 16 + quad * 4 + r;
        if (i < 63) {
            int rl = il * 63 + i;
#pragma unroll
            for (int ct = 0; ct < 4; ++ct)
                PA[(size_t)rl * 64 + ct * 16 + c16] = acc2[ct][r];
            if (c16 == 0) {
                ws[OFF_PM + (imc * 2 + b) * LP + rl] = mrun[r];
                ws[OFF_PD + (imc * 2 + b) * LP + rl] = drun[r];
            }
        }
    }
}

// ---------------- K3b: merge the MH m-slices; result lands in PACC slice 0 ----------------
__global__ void k3b_merge(float* __restrict__ ws) {
    int b = blockIdx.y;
    int l = blockIdx.x * 4 + (threadIdx.x >> 6);
    int c = threadIdx.x & 63;
    if (l >= L_) return;
    float M = -1e30f;
#pragma unroll
    for (int p = 0; p < MH; ++p)
        M = fmaxf(M, ws[OFF_PM + (p * 2 + b) * LP + l]);
    float denom = 0.f, num = 0.f;
#pragma unroll
    for (int p = 0; p < MH; ++p) {
        float w = exp2f((ws[OFF_PM + (p * 2 + b) * LP + l] - M) * LOG2E);
        denom += ws[OFF_PD + (p * 2 + b) * LP + l] * w;
        num += ws[OFF_PACC + ((p * 2 + b) * (size_t)LP + l) * 64 + c] * w;
    }
    ws[OFF_PACC + (b * (size_t)LP + l) * 64 + c] = num / denom;
}

// ---------------- K4: fold + affines + compose output ----------------
__global__ void k4_fold(const float* __restrict__ x, const float* __restrict__ mask,
                        const float* __restrict__ fg_g, const float* __restrict__ fg_b,
                        const float* __restrict__ bg_g, const float* __restrict__ bg_b,
                        const float* __restrict__ wsc, float* __restrict__ out) {
    int gid = blockIdx.x * 256 + threadIdx.x;
    int col = gid & 255, r = (gid >> 8) & 255, c = (gid >> 16) & 63, b = gid >> 22;
    float xv = x[gid];
    float m = mask[b * 65536 + r * 256 + col];
    int imin = (r >= 4) ? ((r - 4) >> 2) : 0;
    int imax = min(62, r >> 2);
    int jmin = (col >= 4) ? ((col - 4) >> 2) : 0;
    int jmax = min(62, col >> 2);
    const float* MF = wsc + OFF_MF + (b * 64 + c) * LP;
    const float* SF = wsc + OFF_SF + (b * 64 + c) * LP;
    const float* NS = wsc + OFF_PACC + b * (size_t)LP * 64;  // merged NSTD (slice 0)
    float folded = 0.f;
    int cnt = (imax - imin + 1) * (jmax - jmin + 1);
    for (int i = imin; i <= imax; ++i)
        for (int j = jmin; j <= jmax; ++j) {
            int l = i * 63 + j;
            float mf = MF[l], sf = SF[l];
            float inf_ = (m != 0.f) ? (xv - mf) / sf : mf;
            folded += NS[l * 64 + c] * (inf_ + 1.f);
        }
    float invm = 1.f - m;
    float ub = (xv * invm * (1.f + bg_g[c]) + bg_b[c]) * invm;
    float nf = (folded / (float)cnt * (1.f + fg_g[c]) + fg_b[c]) * m;
    out[gid] = nf + ub;
}

extern "C" void kernel_launch(void* const* d_in, const int* in_sizes, int n_in,
                              void* d_out, int out_size, void* d_ws, size_t ws_size,
                              hipStream_t stream) {
    const float* x    = (const float*)d_in[0];
    const float* mask = (const float*)d_in[1];
    const float* fg_g = (const float*)d_in[2];
    const float* fg_b = (const float*)d_in[3];
    const float* bg_g = (const float*)d_in[4];
    const float* bg_b = (const float*)d_in[5];
    const float* wf   = (const float*)d_in[6];
    const float* wb   = (const float*)d_in[7];
    const float* rpb  = (const float*)d_in[8];
    float* ws = (float*)d_ws;
    float* out = (float*)d_out;

    k0_w2<<<dim3(64, 2), 256, 0, stream>>>(wf, wb, ws);
    k1_stats<<<dim3(63, 64, 2), 256, 0, stream>>>(x, mask, ws);
    hipMemsetAsync(ws + OFF_TOKF, 0, (size_t)1016832 * sizeof(float), stream);
    k2_tok<<<dim3(63, 4, 2), 256, 0, stream>>>(x, mask, ws, ws);
    k3_attn<<<dim3(63, MH, 2), 256, 0, stream>>>(ws, rpb, ws);
    k3b_merge<<<dim3(993, 2), 256, 0, stream>>>(ws);
    k4_fold<<<dim3(32768), 256, 0, stream>>>(x, mask, fg_g, fg_b, bg_g, bg_b, ws, out);
}